// Round 1
// 601.484 us; speedup vs baseline: 1.0298x; 1.0298x over previous
//
#include <hip/hip_runtime.h>
#include <hip/hip_bf16.h>

#define N_ATOMS 50000
#define N_PAIRS 800000
#define N_EMB   128
#define N_DIST  100
#define N_HID   128
#define TP      128   // pairs per block (8 waves x 16 rows)

typedef __attribute__((ext_vector_type(8))) short bf16x8;
typedef __attribute__((ext_vector_type(4))) float f32x4;

__device__ __forceinline__ short f2b(float x) {
  union { float f; unsigned u; } v; v.f = x;
  unsigned r = (v.u + 0x7FFF + ((v.u >> 16) & 1)) >> 16;   // RNE
  return (short)r;
}
__device__ __forceinline__ float b2f(short b) {
  union { unsigned u; float f; } v; v.u = ((unsigned)(unsigned short)b) << 16;
  return v.f;
}
__device__ __forceinline__ float fast_tanh(float x) {
  // tanh(x) = 1 - 2/(exp2(x*2*log2e)+1); exact at +-inf, ~1e-6 abs error
  const float z = __builtin_amdgcn_exp2f(x * 2.8853900817779268f);
  return 1.f - 2.f * __builtin_amdgcn_rcpf(z + 1.f);
}

// fragment-order index for B operand of mfma_f32_16x16x32_bf16:
// [kstep][ntile][lane=quad*16+n15][j], element (k,n): quad=(k>>3)&3, j=k&7
__device__ __forceinline__ int frag_idx(int k, int n) {
  return ((((k >> 5) * 8 + (n >> 4)) * 64) + (((k >> 3) & 3) * 16) + (n & 15)) * 8 + (k & 7);
}

// async 16B global -> LDS (wave-uniform base + lane*16 pattern)
__device__ __forceinline__ void g2lds16(const void* g, void* l) {
  __builtin_amdgcn_global_load_lds(
      (const __attribute__((address_space(1))) unsigned*)g,
      (__attribute__((address_space(3))) unsigned*)l, 16, 0, 0);
}
// stage 32KB of pre-formatted weights (16384 shorts) with 512 threads
__device__ __forceinline__ void stage_weights(const short* __restrict__ src,
                                              short* WS, int tid) {
  #pragma unroll
  for (int r = 0; r < 4; ++r) {
    const int off = (r * 512 + tid) * 8;   // 8 shorts = 16B per issue
    g2lds16(src + off, WS + off);
  }
}

// ------------- kernel 0: format weights to bf16 fragment order (once) -------
__global__ __launch_bounds__(256) void prep_kernel(
    const float* __restrict__ Wcf, const float* __restrict__ Wdf,
    const float* __restrict__ Wfc, short* __restrict__ Wcf_f,
    short* __restrict__ Wdf_f, short* __restrict__ Wfc_f) {
  const int e = blockIdx.x * 256 + threadIdx.x;   // 16384 total
  const int k = e >> 7, n = e & 127;
  const int fi = frag_idx(k, n);
  Wcf_f[fi] = f2b(Wcf[k * N_HID + n]);
  Wfc_f[fi] = f2b(Wfc[k * N_EMB + n]);
  Wdf_f[fi] = (k < N_DIST) ? f2b(Wdf[k * N_HID + n]) : (short)0;
}

// ---------------- kernel 1: afh = atom_features @ W_cf + b_cf (MFMA) --------
__global__ __launch_bounds__(512) void afh_kernel(
    const float* __restrict__ af, const short* __restrict__ Wcf_f,
    const float* __restrict__ bcf, float* __restrict__ afh) {
  __shared__ short WS[128 * 128];
  const int tid = threadIdx.x;
  const int lane = tid & 63, w = tid >> 6;
  const int lane15 = lane & 15, quad = lane >> 4;
  const int a0 = blockIdx.x * 128;

  stage_weights(Wcf_f, WS, tid);

  f32x4 acc[8];
  #pragma unroll
  for (int nt = 0; nt < 8; ++nt) {
    const float b = bcf[nt * 16 + lane15];
    acc[nt] = (f32x4){b, b, b, b};
  }
  const int arow = min(a0 + w * 16 + lane15, N_ATOMS - 1);
  const float* __restrict__ p = af + (long)arow * N_EMB;
  __syncthreads();                                  // WS staged

  for (int ks = 0; ks < 4; ++ks) {
    const int k0 = ks * 32 + quad * 8;
    const float4 x = *(const float4*)(p + k0);
    const float4 y = *(const float4*)(p + k0 + 4);
    bf16x8 a;
    a[0] = f2b(x.x); a[1] = f2b(x.y); a[2] = f2b(x.z); a[3] = f2b(x.w);
    a[4] = f2b(y.x); a[5] = f2b(y.y); a[6] = f2b(y.z); a[7] = f2b(y.w);
    #pragma unroll
    for (int nt = 0; nt < 8; ++nt) {
      const bf16x8 b = *(const bf16x8*)&WS[((ks * 8 + nt) * 64 + lane) * 8];
      acc[nt] = __builtin_amdgcn_mfma_f32_16x16x32_bf16(a, b, acc[nt], 0, 0, 0);
    }
  }
  #pragma unroll
  for (int reg = 0; reg < 4; ++reg) {
    const int row = a0 + w * 16 + quad * 4 + reg;
    if (row < N_ATOMS) {
      #pragma unroll
      for (int nt = 0; nt < 8; ++nt)
        afh[(long)row * N_HID + nt * 16 + lane15] = acc[nt][reg];
    }
  }
}

// -------- kernel 2: fused MFMA per-pair dh -> h -> tanh(h@Wfc) -> seg-agg ----
// Restructured: all global loads (dist row + afh gather) issued BEFORE the
// first barrier so their latency overlaps; barriers 4 -> 3; segmented
// reduction is now per-wave (16 rows) so no final __syncthreads.
__global__ __launch_bounds__(512, 4) void pair_kernel(
    const float* __restrict__ dist, const int* __restrict__ mi,
    const int* __restrict__ mj, const short* __restrict__ Wdf_f,
    const short* __restrict__ Wfc_f, const float* __restrict__ bdf,
    const float* __restrict__ afh, float* __restrict__ agg) {
  __shared__ short WS[128 * 128];   // 32KB: weights (Wdf then Wfc), frag order
  __shared__ short HS[TP * 128];    // 32KB: h then msg (bf16), xor-swizzled

  const int tid = threadIdx.x;
  const int lane = tid & 63;
  const int w = tid >> 6;           // wave 0..7 -> rows [16w,16w+16)
  const int lane15 = lane & 15;
  const int quad = lane >> 4;
  const long pbase = (long)blockIdx.x * TP;
  const int R = w * 16;

  stage_weights(Wdf_f, WS, tid);    // async

  // ---- prefetch phase-B gather: afh[mj[p]] into registers (32 VGPR) ----
  float g[4][8];
  #pragma unroll
  for (int reg = 0; reg < 4; ++reg) {
    const int r = R + quad * 4 + reg;                 // C-layout row
    const long j = mj[pbase + r];                     // uniform per 16 lanes
    const float* __restrict__ arow = afh + j * N_HID + lane15;
    #pragma unroll
    for (int nt = 0; nt < 8; ++nt)
      g[reg][nt] = arow[nt * 16];                     // 64B-coalesced gather
  }

  // ---- prefetch phase-A operand: full dist row (8 x float4 = 32 VGPR) ----
  const float* __restrict__ drow = dist + (pbase + R + lane15) * (long)N_DIST;
  float4 dx[4], dy[4];
  #pragma unroll
  for (int ks = 0; ks < 3; ++ks) {                    // k0+7 <= 95 < 100
    const int k0 = ks * 32 + quad * 8;
    dx[ks] = *(const float4*)(drow + k0);
    dy[ks] = *(const float4*)(drow + k0 + 4);
  }
  {
    const float4 z = {0.f, 0.f, 0.f, 0.f};
    dx[3] = (quad == 0) ? *(const float4*)(drow + 96) : z;  // k 96..99 valid
    dy[3] = z;                                              // k >= 100 -> 0
  }

  f32x4 acc[8];
  #pragma unroll
  for (int nt = 0; nt < 8; ++nt) {
    const float b = bdf[nt * 16 + lane15];
    acc[nt] = (f32x4){b, b, b, b};
  }
  __syncthreads();                                  // WS = Wdf staged

  // ---- phase A: dh[16x128] = dist_tile @ Wdf + bdf ----
  #pragma unroll
  for (int ks = 0; ks < 4; ++ks) {
    bf16x8 a;
    a[0] = f2b(dx[ks].x); a[1] = f2b(dx[ks].y);
    a[2] = f2b(dx[ks].z); a[3] = f2b(dx[ks].w);
    a[4] = f2b(dy[ks].x); a[5] = f2b(dy[ks].y);
    a[6] = f2b(dy[ks].z); a[7] = f2b(dy[ks].w);
    #pragma unroll
    for (int nt = 0; nt < 8; ++nt) {
      const bf16x8 b = *(const bf16x8*)&WS[((ks * 8 + nt) * 64 + lane) * 8];
      acc[nt] = __builtin_amdgcn_mfma_f32_16x16x32_bf16(a, b, acc[nt], 0, 0, 0);
    }
  }
  __syncthreads();                                  // all waves done reading Wdf

  stage_weights(Wfc_f, WS, tid);                    // async; overlaps phase B

  // ---- phase B: h = dh * afh[mj[p]] (prefetched), bf16 -> HS (swizzled) ----
  #pragma unroll
  for (int reg = 0; reg < 4; ++reg) {
    const int r = R + quad * 4 + reg;               // C-layout row
    #pragma unroll
    for (int nt = 0; nt < 8; ++nt) {
      const int col = nt * 16 + lane15;
      const float h = acc[nt][reg] * g[reg][nt];
      const int ch = (col >> 3) ^ (r & 15);
      HS[(r << 7) + (ch << 3) + (col & 7)] = f2b(h);
    }
  }
  __syncthreads();                                  // Wfc staged, HS visible

  // ---- phase C: msg[16x128] = h @ Wfc ----
  f32x4 acc2[8];
  #pragma unroll
  for (int nt = 0; nt < 8; ++nt) acc2[nt] = (f32x4){0.f, 0.f, 0.f, 0.f};
  const int m = R + lane15;                         // A-layout row
  #pragma unroll
  for (int ks = 0; ks < 4; ++ks) {
    const int ch = (ks * 4 + quad) ^ lane15;        // (m & 15) == lane15
    const bf16x8 a = *(const bf16x8*)&HS[(m << 7) + (ch << 3)];  // 2-way max, free
    #pragma unroll
    for (int nt = 0; nt < 8; ++nt) {
      const bf16x8 b = *(const bf16x8*)&WS[((ks * 8 + nt) * 64 + lane) * 8];
      acc2[nt] = __builtin_amdgcn_mfma_f32_16x16x32_bf16(a, b, acc2[nt], 0, 0, 0);
    }
  }

  // ---- epilogue: tanh -> HS as msg (own rows only) ----
  #pragma unroll
  for (int reg = 0; reg < 4; ++reg) {
    const int r = R + quad * 4 + reg;
    #pragma unroll
    for (int nt = 0; nt < 8; ++nt) {
      const int col = nt * 16 + lane15;
      const float tv = fast_tanh(acc2[nt][reg]);
      const int ch = (col >> 3) ^ (r & 15);
      HS[(r << 7) + (ch << 3) + (col & 7)] = f2b(tv);
    }
  }
  // wave-internal DS RAW: same-wave LDS ops execute in order; fence the
  // compiler's scheduler only (no cross-wave sharing -> no __syncthreads).
  __builtin_amdgcn_wave_barrier();

  // ---- per-wave segmented reduction over sorted mi (16 rows, 2 cols/lane) ----
  {
    const int c0 = lane * 2;                        // cols c0, c0+1 (adjacent)
    const long p0 = pbase + R;
    float s0 = 0.f, s1 = 0.f;
    int cur = mi[p0];                               // wave-uniform value
    for (int rr = 0; rr < 16; ++rr) {
      const int r = R + rr;
      const int idx = mi[p0 + rr];                  // wave-uniform value
      if (idx != cur) {                             // uniform branch at runtime
        atomicAdd(&agg[(size_t)cur * N_EMB + c0], s0);
        atomicAdd(&agg[(size_t)cur * N_EMB + c0 + 1], s1);
        s0 = s1 = 0.f; cur = idx;
      }
      const int ch = (c0 >> 3) ^ (r & 15);          // c0,c0+1 share ch (c0 even)
      const unsigned v =
          *(const unsigned*)&HS[(r << 7) + (ch << 3) + (c0 & 7)];  // 2-way, free
      s0 += b2f((short)(v & 0xFFFF));
      s1 += b2f((short)(v >> 16));
    }
    atomicAdd(&agg[(size_t)cur * N_EMB + c0], s0);
    atomicAdd(&agg[(size_t)cur * N_EMB + c0 + 1], s1);
  }
}

// --- kernel 3: out = agg - tanh((b_df*afh) @ W_fc) + atom_features (MFMA) ---
__global__ __launch_bounds__(512) void out_kernel(
    const float* __restrict__ af, const float* __restrict__ afh,
    const short* __restrict__ Wfc_f, const float* __restrict__ bdf,
    const float* __restrict__ agg, float* __restrict__ out) {
  __shared__ short WS[128 * 128];
  const int tid = threadIdx.x;
  const int lane = tid & 63, w = tid >> 6;
  const int lane15 = lane & 15, quad = lane >> 4;
  const int a0 = blockIdx.x * 128;

  stage_weights(Wfc_f, WS, tid);

  f32x4 acc[8];
  #pragma unroll
  for (int nt = 0; nt < 8; ++nt) acc[nt] = (f32x4){0.f, 0.f, 0.f, 0.f};
  const int arow = min(a0 + w * 16 + lane15, N_ATOMS - 1);
  const float* __restrict__ p = afh + (long)arow * N_HID;
  __syncthreads();                                  // WS staged

  for (int ks = 0; ks < 4; ++ks) {
    const int k0 = ks * 32 + quad * 8;
    const float4 x = *(const float4*)(p + k0);
    const float4 y = *(const float4*)(p + k0 + 4);
    const float4 bx = *(const float4*)(bdf + k0);
    const float4 by = *(const float4*)(bdf + k0 + 4);
    bf16x8 a;
    a[0] = f2b(x.x * bx.x); a[1] = f2b(x.y * bx.y);
    a[2] = f2b(x.z * bx.z); a[3] = f2b(x.w * bx.w);
    a[4] = f2b(y.x * by.x); a[5] = f2b(y.y * by.y);
    a[6] = f2b(y.z * by.z); a[7] = f2b(y.w * by.w);
    #pragma unroll
    for (int nt = 0; nt < 8; ++nt) {
      const bf16x8 b = *(const bf16x8*)&WS[((ks * 8 + nt) * 64 + lane) * 8];
      acc[nt] = __builtin_amdgcn_mfma_f32_16x16x32_bf16(a, b, acc[nt], 0, 0, 0);
    }
  }
  #pragma unroll
  for (int reg = 0; reg < 4; ++reg) {
    const int row = a0 + w * 16 + quad * 4 + reg;
    if (row < N_ATOMS) {
      #pragma unroll
      for (int nt = 0; nt < 8; ++nt) {
        const size_t idx = (size_t)row * N_EMB + nt * 16 + lane15;
        out[idx] = agg[idx] - fast_tanh(acc[nt][reg]) + af[idx];
      }
    }
  }
}

extern "C" void kernel_launch(void* const* d_in, const int* in_sizes, int n_in,
                              void* d_out, int out_size, void* d_ws, size_t ws_size,
                              hipStream_t stream) {
  const float* af   = (const float*)d_in[0];
  const float* dist = (const float*)d_in[1];
  const int*   mi   = (const int*)d_in[3];
  const int*   mj   = (const int*)d_in[4];
  const float* Wcf  = (const float*)d_in[5];
  const float* Wdf  = (const float*)d_in[6];
  const float* Wfc  = (const float*)d_in[7];
  const float* bcf  = (const float*)d_in[8];
  const float* bdf  = (const float*)d_in[9];
  float* out = (float*)d_out;

  float* afh = (float*)d_ws;                        // 25.6 MB
  float* agg = afh + (size_t)N_ATOMS * N_HID;       // 25.6 MB
  short* Wcf_f = (short*)(agg + (size_t)N_ATOMS * N_EMB);  // 3 x 32KB, frag order
  short* Wdf_f = Wcf_f + 128 * 128;
  short* Wfc_f = Wdf_f + 128 * 128;

  hipMemsetAsync(agg, 0, (size_t)N_ATOMS * N_EMB * sizeof(float), stream);
  prep_kernel<<<64, 256, 0, stream>>>(Wcf, Wdf, Wfc, Wcf_f, Wdf_f, Wfc_f);
  afh_kernel<<<(N_ATOMS + 127) / 128, 512, 0, stream>>>(af, Wcf_f, bcf, afh);
  pair_kernel<<<N_PAIRS / TP, 512, 0, stream>>>(dist, mi, mj, Wdf_f, Wfc_f, bdf, afh, agg);
  out_kernel<<<(N_ATOMS + 127) / 128, 512, 0, stream>>>(af, afh, Wfc_f, bdf, agg, out);
}